// Round 1
// baseline (137.069 us; speedup 1.0000x reference)
//
#include <hip/hip_runtime.h>

#define N 512          // n = 2*B
#define B 256
#define D 512
#define TEMP 2.0f
#define NTHREADS 256

// Block i computes row i of everything: distances, logits, exp-logits,
// label diffs, then the masked denominator sums for all k != i, and
// accumulates sum(pos_log_probs) into ws[0] via atomicAdd.
__global__ __launch_bounds__(NTHREADS) void rnc_row_kernel(
    const float* __restrict__ wt, const float* __restrict__ mt,
    const float* __restrict__ lwt, const float* __restrict__ lmt,
    float* __restrict__ partial)
{
    const int i = blockIdx.x;
    const int t = threadIdx.x;

    __shared__ float  sf[D];      // feature row i
    __shared__ float2 sed[N];     // {label_diff, exp_logit} per j
    __shared__ float  slg[N];     // logits per j
    __shared__ float  sred[NTHREADS / 64];

    // ---- load feature row i into LDS (coalesced) ----
    const float* Fi = (i < B) ? (wt + (size_t)i * D) : (mt + (size_t)(i - B) * D);
    for (int d = t; d < D; d += NTHREADS) sf[d] = Fi[d];
    const float lab_i = (i < B) ? lwt[i] : lmt[i - B];
    __syncthreads();

    // ---- phase 1: per-j distance -> logit, exp, label diff ----
    const float4* sf4 = (const float4*)sf;
    #pragma unroll
    for (int jj = 0; jj < N / NTHREADS; ++jj) {
        const int j = t + jj * NTHREADS;
        const float* Fj = (j < B) ? (wt + (size_t)j * D) : (mt + (size_t)(j - B) * D);
        const float4* Fj4 = (const float4*)Fj;
        float acc = 0.f;
        #pragma unroll 4
        for (int d4 = 0; d4 < D / 4; ++d4) {
            float4 a = sf4[d4];
            float4 b = Fj4[d4];
            float dx = a.x - b.x, dy = a.y - b.y, dz = a.z - b.z, dw = a.w - b.w;
            acc += dx * dx + dy * dy + dz * dz + dw * dw;
        }
        const float dist = (acc > 0.f) ? sqrtf(acc) : 0.f;
        const float lg = -dist / TEMP;          // row-max is diag logit == 0, so no shift needed
        slg[j] = lg;
        const float lab_j = (j < B) ? lwt[j] : lmt[j - B];
        const float e = (j == i) ? 0.f : __expf(lg);  // zero diagonal: drops j==i from denom
        sed[j] = make_float2(fabsf(lab_i - lab_j), e);
    }
    __syncthreads();

    // ---- phase 2: each lane owns k; j-loop is wave-uniform (LDS broadcast) ----
    float local = 0.f;
    #pragma unroll
    for (int kk = 0; kk < N / NTHREADS; ++kk) {
        const int k = t + kk * NTHREADS;
        if (k == i) continue;
        const float ldk = sed[k].x;
        float denom = 0.f;
        #pragma unroll 8
        for (int j = 0; j < N; ++j) {
            float2 v = sed[j];               // uniform address -> broadcast read
            denom += (v.x >= ldk) ? v.y : 0.f;
        }
        local += slg[k] - __logf(denom);
    }

    // ---- block reduction + atomic accumulate ----
    #pragma unroll
    for (int off = 32; off > 0; off >>= 1)
        local += __shfl_down(local, off, 64);
    if ((t & 63) == 0) sred[t >> 6] = local;
    __syncthreads();
    if (t == 0) {
        float s = 0.f;
        #pragma unroll
        for (int w = 0; w < NTHREADS / 64; ++w) s += sred[w];
        atomicAdd(partial, s);
    }
}

__global__ void rnc_finalize(const float* __restrict__ partial, float* __restrict__ out)
{
    out[0] = -partial[0] / (float)((long)N * (N - 1));
}

extern "C" void kernel_launch(void* const* d_in, const int* in_sizes, int n_in,
                              void* d_out, int out_size, void* d_ws, size_t ws_size,
                              hipStream_t stream) {
    const float* wt  = (const float*)d_in[0];
    const float* mt  = (const float*)d_in[1];
    const float* lwt = (const float*)d_in[2];
    const float* lmt = (const float*)d_in[3];
    float* out = (float*)d_out;
    float* ws  = (float*)d_ws;

    hipMemsetAsync(ws, 0, sizeof(float), stream);   // ws is re-poisoned to 0xAA each call
    rnc_row_kernel<<<N, NTHREADS, 0, stream>>>(wt, mt, lwt, lmt, ws);
    rnc_finalize<<<1, 1, 0, stream>>>(ws, out);
}

// Round 2
// 103.886 us; speedup vs baseline: 1.3194x; 1.3194x over previous
//
#include <hip/hip_runtime.h>

#define N 512          // n = 2*B
#define B 256
#define D 512
#define NTHREADS 256

// Block i handles row i:
//  phase 1: coalesced pairwise distances (16 lanes cooperate per j, row i in regs)
//  phase 2: bitonic sort by label-diff + suffix scan -> denom per k in O(n log^2 n)
__global__ __launch_bounds__(NTHREADS) void rnc_row_kernel(
    const float* __restrict__ wt, const float* __restrict__ mt,
    const float* __restrict__ lwt, const float* __restrict__ lmt,
    float* __restrict__ partial)
{
    const int i    = blockIdx.x;
    const int t    = threadIdx.x;
    const int lane = t & 63;
    const int w    = t >> 6;      // wave 0..3
    const int g    = lane >> 4;   // 16-lane group 0..3
    const int s    = lane & 15;   // sublane 0..15

    __shared__ float slab[N];                  // labels
    __shared__ unsigned long long skey[N];     // (ld_bits<<32)|j, sorted ascending
    __shared__ float se[N];                    // exp-logit by j (unsorted)
    __shared__ float ss[N];                    // suffix-scan array (sorted order)
    __shared__ float sred[NTHREADS / 64];

    // ---- labels into LDS ----
    for (int j = t; j < N; j += NTHREADS)
        slab[j] = (j < B) ? lwt[j] : lmt[j - B];
    __syncthreads();
    const float li = slab[i];

    // ---- preload row i into registers: chunk c = s + 16*q (32 floats/lane) ----
    const float* Fi = (i < B) ? (wt + (size_t)i * D) : (mt + (size_t)(i - B) * D);
    const float4* Fi4 = (const float4*)Fi;
    float4 fr[8];
    #pragma unroll
    for (int q = 0; q < 8; ++q) fr[q] = Fi4[s + 16 * q];

    // ---- phase 1: each (wave,group) owns j = (w*4+g) + 16*m ----
    float lg_sum = 0.f;    // accumulates sum of logits over this thread's rows
    for (int m = 0; m < N / 16; ++m) {
        const int j = (w * 4 + g) + 16 * m;
        const float* Fj = (j < B) ? (wt + (size_t)j * D) : (mt + (size_t)(j - B) * D);
        const float4* Fj4 = (const float4*)Fj;
        float acc = 0.f;
        #pragma unroll
        for (int q = 0; q < 8; ++q) {
            float4 b = Fj4[s + 16 * q];   // 16 lanes x 16B contiguous: coalesced
            float dx = fr[q].x - b.x, dy = fr[q].y - b.y;
            float dz = fr[q].z - b.z, dw = fr[q].w - b.w;
            acc += dx * dx + dy * dy + dz * dz + dw * dw;
        }
        acc += __shfl_down(acc, 8, 16);
        acc += __shfl_down(acc, 4, 16);
        acc += __shfl_down(acc, 2, 16);
        acc += __shfl_down(acc, 1, 16);
        if (s == 0) {
            const float dist = (acc > 0.f) ? sqrtf(acc) : 0.f;
            const float lg = -dist * 0.5f;     // temp = 2; row max (diag) is 0 -> no shift
            lg_sum += lg;                       // lg[i]==0, harmless to include
            const float e = (j == i) ? 0.f : __expf(lg);
            const float ld = fabsf(li - slab[j]);
            se[j] = e;
            skey[j] = ((unsigned long long)__float_as_uint(ld) << 32) | (unsigned int)j;
        }
    }

    // ---- phase 2a: bitonic sort skey ascending (512 elems, 256 threads) ----
    for (int k = 2; k <= N; k <<= 1) {
        for (int jj = k >> 1; jj > 0; jj >>= 1) {
            __syncthreads();
            #pragma unroll
            for (int p = 0; p < 2; ++p) {
                const int pos = t + p * NTHREADS;
                const int partner = pos ^ jj;
                if (partner > pos) {
                    const bool asc = ((pos & k) == 0);
                    unsigned long long a = skey[pos];
                    unsigned long long b = skey[partner];
                    const bool do_swap = asc ? (a > b) : (a < b);
                    if (do_swap) { skey[pos] = b; skey[partner] = a; }
                }
            }
        }
    }
    __syncthreads();

    // ---- phase 2b: gather e into sorted order ----
    #pragma unroll
    for (int p = 0; p < 2; ++p) {
        const int pos = t + p * NTHREADS;
        const int j = (int)(skey[pos] & 0xffffffffu);
        ss[pos] = se[j];
    }
    __syncthreads();

    // ---- phase 2c: inclusive suffix scan of ss (Hillis-Steele) ----
    for (int d = 1; d < N; d <<= 1) {
        const float v0 = ss[t] + ((t + d < N) ? ss[t + d] : 0.f);
        const float v1 = ss[t + NTHREADS] +
                         ((t + NTHREADS + d < N) ? ss[t + NTHREADS + d] : 0.f);
        __syncthreads();
        ss[t] = v0;
        ss[t + NTHREADS] = v1;
        __syncthreads();
    }

    // ---- phase 2d: denom per rank (tie-aware), accumulate -log(denom) ----
    float local = lg_sum;
    #pragma unroll
    for (int p = 0; p < 2; ++p) {
        const int pos = t + p * NTHREADS;
        const unsigned long long key = skey[pos];
        const int j = (int)(key & 0xffffffffu);
        if (j != i) {
            const unsigned int hi = (unsigned int)(key >> 32);
            int r = pos;   // walk back over ties (rare: random labels)
            while (r > 0 && (unsigned int)(skey[r - 1] >> 32) == hi) --r;
            local -= __logf(ss[r]);     // denom = suffix sum from first tie rank
        }
    }

    // ---- block reduction + atomic ----
    #pragma unroll
    for (int off = 32; off > 0; off >>= 1)
        local += __shfl_down(local, off, 64);
    if (lane == 0) sred[w] = local;
    __syncthreads();
    if (t == 0) {
        float sum = 0.f;
        #pragma unroll
        for (int v = 0; v < NTHREADS / 64; ++v) sum += sred[v];
        atomicAdd(partial, sum);
    }
}

__global__ void rnc_finalize(const float* __restrict__ partial, float* __restrict__ out)
{
    out[0] = -partial[0] / (float)((long)N * (N - 1));
}

extern "C" void kernel_launch(void* const* d_in, const int* in_sizes, int n_in,
                              void* d_out, int out_size, void* d_ws, size_t ws_size,
                              hipStream_t stream) {
    const float* wt  = (const float*)d_in[0];
    const float* mt  = (const float*)d_in[1];
    const float* lwt = (const float*)d_in[2];
    const float* lmt = (const float*)d_in[3];
    float* out = (float*)d_out;
    float* ws  = (float*)d_ws;

    hipMemsetAsync(ws, 0, sizeof(float), stream);   // ws is re-poisoned each call
    rnc_row_kernel<<<N, NTHREADS, 0, stream>>>(wt, mt, lwt, lmt, ws);
    rnc_finalize<<<1, 1, 0, stream>>>(ws, out);
}

// Round 3
// 103.330 us; speedup vs baseline: 1.3265x; 1.0054x over previous
//
#include <hip/hip_runtime.h>

#define N 512          // n = 2*B
#define B 256
#define D 512
#define NTHREADS 256

// ws layout (floats):
#define WS_SL    0        // [N]  sorted labels (ascending)
#define WS_RANK  N        // [N]  rank of original index j (stored as int)
#define WS_PART  (2 * N)  // [N]  per-block partial sums

// ---- kernel 1: counting rank of each label (stable by index) ----
__global__ __launch_bounds__(N) void rank_kernel(
    const float* __restrict__ lwt, const float* __restrict__ lmt,
    float* __restrict__ ws)
{
    const int t = threadIdx.x;               // 0..511
    __shared__ float slab[N];
    slab[t] = (t < B) ? lwt[t] : lmt[t - B];
    __syncthreads();
    const float lj = slab[t];
    int r = 0;
    #pragma unroll 8
    for (int x = 0; x < N; ++x) {
        const float v = slab[x];             // wave-uniform LDS read (broadcast)
        r += (v < lj || (v == lj && x < t)) ? 1 : 0;
    }
    ws[WS_SL + r] = lj;                      // sorted labels
    ((int*)ws)[WS_RANK + t] = r;             // rank[orig j]
}

// ---- kernel 2: one block per row i ----
__global__ __launch_bounds__(NTHREADS) void rnc_row_kernel(
    const float* __restrict__ wt, const float* __restrict__ mt,
    const float* __restrict__ lwt, const float* __restrict__ lmt,
    float* __restrict__ ws)
{
    const int i    = blockIdx.x;
    const int t    = threadIdx.x;
    const int lane = t & 63;
    const int w    = t >> 6;      // wave 0..3
    const int g    = lane >> 4;   // 16-lane group 0..3
    const int s    = lane & 15;   // sublane 0..15

    __shared__ float sl[N];       // sorted labels
    __shared__ int   srk[N];      // rank by original j
    __shared__ float sp[N];       // e in sorted order -> prefix-inclusive scan
    __shared__ float ssf[N];      // e in sorted order -> suffix-inclusive scan
    __shared__ float sred[NTHREADS / 64];

    for (int x = t; x < N; x += NTHREADS) {
        sl[x]  = ws[WS_SL + x];
        srk[x] = ((const int*)ws)[WS_RANK + x];
    }
    const float li = (i < B) ? lwt[i] : lmt[i - B];

    // preload row i into registers: chunk = s + 16*q (32 floats/lane)
    const float* Fi = (i < B) ? (wt + (size_t)i * D) : (mt + (size_t)(i - B) * D);
    const float4* Fi4 = (const float4*)Fi;
    float4 fr[8];
    #pragma unroll
    for (int q = 0; q < 8; ++q) fr[q] = Fi4[s + 16 * q];
    __syncthreads();

    // ---- phase 1: distances -> e, scattered into sorted-label order ----
    float lg_sum = 0.f;
    for (int m = 0; m < N / 16; ++m) {
        const int j = (w * 4 + g) + 16 * m;
        const float* Fj = (j < B) ? (wt + (size_t)j * D) : (mt + (size_t)(j - B) * D);
        const float4* Fj4 = (const float4*)Fj;
        float acc = 0.f;
        #pragma unroll
        for (int q = 0; q < 8; ++q) {
            float4 b = Fj4[s + 16 * q];      // 16 lanes x 16B contiguous: coalesced
            float dx = fr[q].x - b.x, dy = fr[q].y - b.y;
            float dz = fr[q].z - b.z, dw = fr[q].w - b.w;
            acc += dx * dx + dy * dy + dz * dz + dw * dw;
        }
        acc += __shfl_down(acc, 8, 16);
        acc += __shfl_down(acc, 4, 16);
        acc += __shfl_down(acc, 2, 16);
        acc += __shfl_down(acc, 1, 16);
        if (s == 0) {
            const float dist = (acc > 0.f) ? sqrtf(acc) : 0.f;
            const float lg = -dist * 0.5f;   // temp=2; row max (diag logit) is 0
            lg_sum += lg;                    // lg[i]==0, harmless to include
            const float e = (j == i) ? 0.f : __expf(lg);
            const int pos = srk[j];
            sp[pos]  = e;
            ssf[pos] = e;
        }
    }
    __syncthreads();

    // ---- phase 2a: inclusive prefix (sp) and suffix (ssf) scans, fused ----
    for (int d = 1; d < N; d <<= 1) {
        const int x0 = t, x1 = t + NTHREADS;
        const float aP0 = (x0 >= d) ? sp[x0 - d] : 0.f;
        const float aP1 = (x1 >= d) ? sp[x1 - d] : 0.f;
        const float aS0 = (x0 + d < N) ? ssf[x0 + d] : 0.f;
        const float aS1 = (x1 + d < N) ? ssf[x1 + d] : 0.f;
        const float cP0 = sp[x0], cP1 = sp[x1];
        const float cS0 = ssf[x0], cS1 = ssf[x1];
        __syncthreads();
        sp[x0]  = cP0 + aP0;  sp[x1]  = cP1 + aP1;
        ssf[x0] = cS0 + aS0;  ssf[x1] = cS1 + aS1;
        __syncthreads();
    }

    // ---- phase 2b: per-k denom via two exact binary searches ----
    const int ri = srk[i];        // sorted position of row i (sl[ri] == li)
    float local = lg_sum;
    #pragma unroll
    for (int p = 0; p < 2; ++p) {
        const int x = t + p * NTHREADS;      // sorted position of k
        if (x == ri) continue;
        const float th = fabsf(li - sl[x]);  // == reference ld_k exactly
        // left branch [0, ri]: fabsf(li - sl[.]) weakly decreasing.
        // a = first idx with predicate false -> prefix [0, a) included.
        int lo = 0, hi = ri + 1;
        while (lo < hi) {
            const int mid = (lo + hi) >> 1;
            if (fabsf(li - sl[mid]) >= th) lo = mid + 1; else hi = mid;
        }
        const int a = lo;
        // right branch [ri+1, N): weakly increasing.
        // b = first idx with predicate true -> suffix [b, N) included.
        lo = ri + 1; hi = N;
        while (lo < hi) {
            const int mid = (lo + hi) >> 1;
            if (fabsf(li - sl[mid]) >= th) hi = mid; else lo = mid + 1;
        }
        const int b = lo;
        const float denom = ((a > 0) ? sp[a - 1] : 0.f) + ((b < N) ? ssf[b] : 0.f);
        local -= __logf(denom);
    }

    // ---- block reduction, plain store (no atomic, no memset needed) ----
    #pragma unroll
    for (int off = 32; off > 0; off >>= 1)
        local += __shfl_down(local, off, 64);
    if (lane == 0) sred[w] = local;
    __syncthreads();
    if (t == 0) {
        float sum = 0.f;
        #pragma unroll
        for (int v = 0; v < NTHREADS / 64; ++v) sum += sred[v];
        ws[WS_PART + i] = sum;
    }
}

// ---- kernel 3: reduce partials + finalize ----
__global__ __launch_bounds__(NTHREADS) void rnc_finalize(
    const float* __restrict__ ws, float* __restrict__ out)
{
    const int t = threadIdx.x;
    __shared__ float sred[NTHREADS / 64];
    float v = ws[WS_PART + t] + ws[WS_PART + t + NTHREADS];
    #pragma unroll
    for (int off = 32; off > 0; off >>= 1)
        v += __shfl_down(v, off, 64);
    if ((t & 63) == 0) sred[t >> 6] = v;
    __syncthreads();
    if (t == 0) {
        float sum = 0.f;
        #pragma unroll
        for (int k = 0; k < NTHREADS / 64; ++k) sum += sred[k];
        out[0] = -sum / (float)((long)N * (N - 1));
    }
}

extern "C" void kernel_launch(void* const* d_in, const int* in_sizes, int n_in,
                              void* d_out, int out_size, void* d_ws, size_t ws_size,
                              hipStream_t stream) {
    const float* wt  = (const float*)d_in[0];
    const float* mt  = (const float*)d_in[1];
    const float* lwt = (const float*)d_in[2];
    const float* lmt = (const float*)d_in[3];
    float* out = (float*)d_out;
    float* ws  = (float*)d_ws;

    rank_kernel<<<1, N, 0, stream>>>(lwt, lmt, ws);
    rnc_row_kernel<<<N, NTHREADS, 0, stream>>>(wt, mt, lwt, lmt, ws);
    rnc_finalize<<<1, NTHREADS, 0, stream>>>(ws, out);
}

// Round 4
// 81.374 us; speedup vs baseline: 1.6844x; 1.2698x over previous
//
#include <hip/hip_runtime.h>

#define N 512          // n = 2*B
#define B 256
#define D 512
#define NT 512         // block size for rank + main kernels
#define NBLK (N / 2)   // 256 main blocks, 2 rows each

// ws layout (floats)
#define WS_SL    0          // [N]  sorted labels ascending
#define WS_RANK  N          // [N]  int rank of original index j
#define WS_NORM  (2 * N)    // [N]  ||f_j||^2
#define WS_PART  (3 * N)    // [NBLK] per-block partial sums

// ---- kernel 1 (grid 16): counting rank + row norms ----
__global__ __launch_bounds__(NT) void rank_norm_kernel(
    const float* __restrict__ wt, const float* __restrict__ mt,
    const float* __restrict__ lwt, const float* __restrict__ lmt,
    float* __restrict__ ws)
{
    const int t = threadIdx.x, b = blockIdx.x;
    __shared__ float slab[N];
    __shared__ int scnt[32];
    slab[t] = (t < B) ? lwt[t] : lmt[t - B];
    if (t < 32) scnt[t] = 0;
    __syncthreads();

    // rank of j = b*32 + (t&31); chunk c = t>>5 covers x in [c*32, c*32+32)
    const int jj = t & 31, j = b * 32 + jj, c = t >> 5;
    const float lj = slab[j];
    int r = 0;
    #pragma unroll 8
    for (int x = c * 32; x < c * 32 + 32; ++x) {
        const float v = slab[x];   // <=2 distinct addrs per wave: conflict-free
        r += (v < lj || (v == lj && x < j)) ? 1 : 0;
    }
    atomicAdd(&scnt[jj], r);

    // norms: rows [b*32, b*32+32), 16 lanes per row (coalesced 256B)
    const int row = b * 32 + (t >> 4), s16 = t & 15;
    const float* F = (row < B) ? (wt + (size_t)row * D) : (mt + (size_t)(row - B) * D);
    const float4* F4 = (const float4*)F;
    float nacc = 0.f;
    #pragma unroll
    for (int q = 0; q < 8; ++q) {
        const float4 v = F4[s16 + 16 * q];
        nacc += v.x * v.x + v.y * v.y + v.z * v.z + v.w * v.w;
    }
    nacc += __shfl_down(nacc, 8, 16);
    nacc += __shfl_down(nacc, 4, 16);
    nacc += __shfl_down(nacc, 2, 16);
    nacc += __shfl_down(nacc, 1, 16);
    if (s16 == 0) ws[WS_NORM + row] = nacc;

    __syncthreads();
    if (t < 32) {
        const int r2 = scnt[t], j2 = b * 32 + t;
        ws[WS_SL + r2] = slab[j2];
        ((int*)ws)[WS_RANK + j2] = r2;
    }
}

// ---- kernel 2 (grid 256): 2 rows per block, fused dist + scan + search ----
__global__ __launch_bounds__(NT) void rnc_main(
    const float* __restrict__ wt, const float* __restrict__ mt,
    const float* __restrict__ lwt, const float* __restrict__ lmt,
    float* __restrict__ ws)
{
    const int b = blockIdx.x, i0 = 2 * b, i1 = 2 * b + 1;
    const int t = threadIdx.x;
    const int w = t >> 6, lane = t & 63, g = lane >> 4, s = lane & 15;

    __shared__ float sl[N];
    __shared__ int   srk[N];
    __shared__ float snm[N];
    __shared__ __align__(16) float sp0[N];   // row0 prefix-scan array
    __shared__ __align__(16) float sf0[N];   // row0 suffix-scan array
    __shared__ __align__(16) float sp1[N];
    __shared__ __align__(16) float sf1[N];
    __shared__ float sred[NT / 64];

    sl[t]  = ws[WS_SL + t];
    srk[t] = ((const int*)ws)[WS_RANK + t];
    snm[t] = ws[WS_NORM + t];

    // preload rows i0, i1 (32 floats each per lane, chunk = s + 16q)
    const float* Fi0 = (i0 < B) ? (wt + (size_t)i0 * D) : (mt + (size_t)(i0 - B) * D);
    const float* Fi1 = (i1 < B) ? (wt + (size_t)i1 * D) : (mt + (size_t)(i1 - B) * D);
    const float4* Fi04 = (const float4*)Fi0;
    const float4* Fi14 = (const float4*)Fi1;
    float4 fr0[8], fr1[8];
    #pragma unroll
    for (int q = 0; q < 8; ++q) { fr0[q] = Fi04[s + 16 * q]; fr1[q] = Fi14[s + 16 * q]; }
    const float li0 = (i0 < B) ? lwt[i0] : lmt[i0 - B];
    const float li1 = (i1 < B) ? lwt[i1] : lmt[i1 - B];
    __syncthreads();
    const float ni0 = snm[i0], ni1 = snm[i1];

    // ---- phase 1: Gram-form distances, scatter e into sorted order ----
    float lg_acc = 0.f;
    const int wg = w * 4 + g;                 // 0..31
    for (int m = 0; m < 16; ++m) {
        const int j = wg + 32 * m;
        const float* Fj = (j < B) ? (wt + (size_t)j * D) : (mt + (size_t)(j - B) * D);
        const float4* Fj4 = (const float4*)Fj;
        float a0 = 0.f, a1 = 0.f;
        #pragma unroll
        for (int q = 0; q < 8; ++q) {
            const float4 v = Fj4[s + 16 * q];
            a0 += fr0[q].x * v.x + fr0[q].y * v.y + fr0[q].z * v.z + fr0[q].w * v.w;
            a1 += fr1[q].x * v.x + fr1[q].y * v.y + fr1[q].z * v.z + fr1[q].w * v.w;
        }
        a0 += __shfl_down(a0, 8, 16); a1 += __shfl_down(a1, 8, 16);
        a0 += __shfl_down(a0, 4, 16); a1 += __shfl_down(a1, 4, 16);
        a0 += __shfl_down(a0, 2, 16); a1 += __shfl_down(a1, 2, 16);
        a0 += __shfl_down(a0, 1, 16); a1 += __shfl_down(a1, 1, 16);
        if (s == 0) {
            const float nj = snm[j];
            const float d0 = fmaxf(ni0 + nj - 2.f * a0, 0.f);
            const float d1 = fmaxf(ni1 + nj - 2.f * a1, 0.f);
            const float lg0 = -0.5f * sqrtf(d0);
            const float lg1 = -0.5f * sqrtf(d1);
            lg_acc += lg0 + lg1;              // diag term ~ -1e-3 noise, /261k later
            const int pos = srk[j];
            const float e0 = (j == i0) ? 0.f : __expf(lg0);
            const float e1 = (j == i1) ? 0.f : __expf(lg1);
            sp0[pos] = e0; sf0[pos] = e0;
            sp1[pos] = e1; sf1[pos] = e1;
        }
    }
    __syncthreads();

    // ---- phase 2a: wave-parallel scans (no block barriers inside) ----
    if (w < 4) {
        float* arr = (w == 0) ? sp0 : (w == 1) ? sf0 : (w == 2) ? sp1 : sf1;
        float4* a4 = (float4*)arr;
        float4 u0 = a4[lane * 2], u1 = a4[lane * 2 + 1];
        float v0 = u0.x, v1 = u0.y, v2 = u0.z, v3 = u0.w;
        float v4 = u1.x, v5 = u1.y, v6 = u1.z, v7 = u1.w;
        if ((w & 1) == 0) {                    // inclusive prefix scan
            v1 += v0; v2 += v1; v3 += v2; v4 += v3; v5 += v4; v6 += v5; v7 += v6;
            float x = v7;
            #pragma unroll
            for (int off = 1; off < 64; off <<= 1) {
                const float y = __shfl_up(x, off, 64);
                if (lane >= off) x += y;
            }
            float ex = __shfl_up(x, 1, 64);
            if (lane == 0) ex = 0.f;
            v0 += ex; v1 += ex; v2 += ex; v3 += ex; v4 += ex; v5 += ex; v6 += ex; v7 += ex;
        } else {                               // inclusive suffix scan
            v6 += v7; v5 += v6; v4 += v5; v3 += v4; v2 += v3; v1 += v2; v0 += v1;
            float x = v0;
            #pragma unroll
            for (int off = 1; off < 64; off <<= 1) {
                const float y = __shfl_down(x, off, 64);
                if (lane + off < 64) x += y;
            }
            float ex = __shfl_down(x, 1, 64);
            if (lane == 63) ex = 0.f;
            v0 += ex; v1 += ex; v2 += ex; v3 += ex; v4 += ex; v5 += ex; v6 += ex; v7 += ex;
        }
        a4[lane * 2]     = make_float4(v0, v1, v2, v3);
        a4[lane * 2 + 1] = make_float4(v4, v5, v6, v7);
    }
    __syncthreads();

    // ---- phase 2b: per-k denom via two exact binary searches ----
    const int ri0 = srk[i0], ri1 = srk[i1];
    float local = lg_acc;
    #pragma unroll
    for (int p = 0; p < 2; ++p) {
        const int idx = t + p * NT;           // 0..1023
        const int row = idx >> 9;             // wave-uniform
        const int x = idx & (N - 1);
        const int ri = row ? ri1 : ri0;
        const float li = row ? li1 : li0;
        const float* SP = row ? sp1 : sp0;
        const float* SF = row ? sf1 : sf0;
        if (x != ri) {
            const float th = fabsf(li - sl[x]);
            int lo = 0, hi = ri + 1;          // left branch: weakly decreasing
            while (lo < hi) {
                const int mid = (lo + hi) >> 1;
                if (fabsf(li - sl[mid]) >= th) lo = mid + 1; else hi = mid;
            }
            const int a = lo;
            lo = ri + 1; hi = N;              // right branch: weakly increasing
            while (lo < hi) {
                const int mid = (lo + hi) >> 1;
                if (fabsf(li - sl[mid]) >= th) hi = mid; else lo = mid + 1;
            }
            const int bb = lo;
            const float denom = ((a > 0) ? SP[a - 1] : 0.f) + ((bb < N) ? SF[bb] : 0.f);
            local -= __logf(denom);
        }
    }

    // ---- block reduction, plain store ----
    #pragma unroll
    for (int off = 32; off > 0; off >>= 1)
        local += __shfl_down(local, off, 64);
    if (lane == 0) sred[w] = local;
    __syncthreads();
    if (t == 0) {
        float sum = 0.f;
        #pragma unroll
        for (int k = 0; k < NT / 64; ++k) sum += sred[k];
        ws[WS_PART + b] = sum;
    }
}

// ---- kernel 3: reduce 256 partials + finalize ----
__global__ __launch_bounds__(NBLK) void rnc_finalize(
    const float* __restrict__ ws, float* __restrict__ out)
{
    const int t = threadIdx.x;
    __shared__ float sred[NBLK / 64];
    float v = ws[WS_PART + t];
    #pragma unroll
    for (int off = 32; off > 0; off >>= 1)
        v += __shfl_down(v, off, 64);
    if ((t & 63) == 0) sred[t >> 6] = v;
    __syncthreads();
    if (t == 0) {
        float sum = 0.f;
        #pragma unroll
        for (int k = 0; k < NBLK / 64; ++k) sum += sred[k];
        out[0] = -sum / (float)((long)N * (N - 1));
    }
}

extern "C" void kernel_launch(void* const* d_in, const int* in_sizes, int n_in,
                              void* d_out, int out_size, void* d_ws, size_t ws_size,
                              hipStream_t stream) {
    const float* wt  = (const float*)d_in[0];
    const float* mt  = (const float*)d_in[1];
    const float* lwt = (const float*)d_in[2];
    const float* lmt = (const float*)d_in[3];
    float* out = (float*)d_out;
    float* ws  = (float*)d_ws;

    rank_norm_kernel<<<16, NT, 0, stream>>>(wt, mt, lwt, lmt, ws);
    rnc_main<<<NBLK, NT, 0, stream>>>(wt, mt, lwt, lmt, ws);
    rnc_finalize<<<1, NBLK, 0, stream>>>(ws, out);
}